// Round 10
// baseline (273.684 us; speedup 1.0000x reference)
//
#include <hip/hip_runtime.h>

typedef __bf16 bf16;
typedef bf16 bf16x4 __attribute__((ext_vector_type(4)));
typedef bf16 bf16x8 __attribute__((ext_vector_type(8)));
typedef unsigned short u16x8 __attribute__((ext_vector_type(8)));
typedef float f32x4 __attribute__((ext_vector_type(4)));

#define Bb 2
#define Ss 2048
#define Hh 2048
#define NHh 16
#define HNd 128
#define H3 6144
#define Mm 4096
#define SCALE_QK 0.08838834764831843f  // 1/sqrt(128)

__device__ __forceinline__ void async_copy16(void* lds, const void* g) {
  __builtin_amdgcn_global_load_lds(
      (const __attribute__((address_space(1))) unsigned int*)g,
      (__attribute__((address_space(3))) unsigned int*)lds, 16, 0, 0);
}

template <int N>
__device__ __forceinline__ void waitvm() {
  if constexpr (N == 0) asm volatile("s_waitcnt vmcnt(0)" ::: "memory");
  else if constexpr (N == 2) asm volatile("s_waitcnt vmcnt(2)" ::: "memory");
  else if constexpr (N == 3) asm volatile("s_waitcnt vmcnt(3)" ::: "memory");
  // N==9: no wait
}

// ---------------- fused fp32 -> bf16 convert (3 segments, 1 launch) ----------------
__device__ __forceinline__ void cvt4(const float* in, bf16* out, int i) {
  float4 v = *reinterpret_cast<const float4*>(in + i);
  bf16x4 o;
  o[0] = (bf16)v.x; o[1] = (bf16)v.y; o[2] = (bf16)v.z; o[3] = (bf16)v.w;
  *reinterpret_cast<bf16x4*>(out + i) = o;
}

__global__ __launch_bounds__(256) void cvt3_kernel(
    const float* __restrict__ s0, bf16* __restrict__ d0, int n0,
    const float* __restrict__ s1, bf16* __restrict__ d1, int n1,
    const float* __restrict__ s2, bf16* __restrict__ d2, int n2) {
  int i = (blockIdx.x * 256 + threadIdx.x) * 4;
  if (i < n0) cvt4(s0, d0, i);
  else if ((i -= n0) < n1) cvt4(s1, d1, i);
  else if ((i -= n1) < n2) cvt4(s2, d2, i);
}

// ---------------- 256xBN 8-phase bf16 GEMM (T1+T2+T3+T4+T5), BN = NJ*64 ----------------
template <int NJ>
struct GFrags {
  bf16x8 af[2][2];
  bf16x8 bfr[NJ][2];
};

template <int NJ, int MP, int RDB>
__device__ __forceinline__ void g_reads(const bf16* asb, const bf16* bsb,
                                        int lm, int lg, int wm, int wn,
                                        GFrags<NJ>& f) {
  if (RDB) {
#pragma unroll
    for (int nj = 0; nj < NJ; ++nj)
#pragma unroll
      for (int kk = 0; kk < 2; ++kk) {
        const int row = wn * (NJ * 16) + nj * 16 + lm;
        f.bfr[nj][kk] = *reinterpret_cast<const bf16x8*>(
            (const char*)bsb + row * 128 + ((kk * 64 + lg * 16) ^ ((lm & 7) << 4)));
      }
  }
#pragma unroll
  for (int i = 0; i < 2; ++i)
#pragma unroll
    for (int kk = 0; kk < 2; ++kk) {
      const int row = wm * 128 + (MP * 2 + i) * 16 + lm;
      f.af[i][kk] = *reinterpret_cast<const bf16x8*>(
          (const char*)asb + row * 128 + ((kk * 64 + lg * 16) ^ ((lm & 7) << 4)));
    }
}

template <int NJ, int MP>
__device__ __forceinline__ void g_mfma(const GFrags<NJ>& f, f32x4 (&acc)[8][NJ]) {
#pragma unroll
  for (int kk = 0; kk < 2; ++kk)
#pragma unroll
    for (int i = 0; i < 2; ++i)
#pragma unroll
      for (int nj = 0; nj < NJ; ++nj)
        acc[MP * 2 + i][nj] = __builtin_amdgcn_mfma_f32_16x16x32_bf16(
            f.af[i][kk], f.bfr[nj][kk], acc[MP * 2 + i][nj], 0, 0, 0);
}

template <int NJ, int OUT_F32>
__global__ __launch_bounds__(512, 2) void gemmW_kernel(
    const bf16* __restrict__ A, const bf16* __restrict__ Bw,
    const float* __restrict__ bias, void* __restrict__ Cout,
    int M, int N, int K) {
  __shared__ __align__(16) bf16 As[2][256 * 64];
  __shared__ __align__(16) bf16 Bs[2][NJ * 64 * 64];

  const int tid = threadIdx.x;
  const int lane = tid & 63;
  const int w = tid >> 6;
  const int wm = w >> 2, wn = w & 3;
  const int lm = lane & 15, lg = lane >> 4;
  const int srow = lane >> 3;
  const int sslot = lane & 7;

  // XCD column-chunk remap (bijective when gridDim.x % 8 == 0)
  const int id = blockIdx.y * gridDim.x + blockIdx.x;
  const int cpx = gridDim.x >> 3;
  const int xcd = id & 7, rem = id >> 3;
  const int bx = xcd * cpx + rem % cpx;
  const int by = rem / cpx;
  const int m0 = by * 256, n0 = bx * (NJ * 64);

  auto stageA = [&](int b, int t) {
#pragma unroll
    for (int l = 0; l < 4; ++l) {
      const int r = l * 64 + w * 8 + srow;
      async_copy16((char*)&As[b][0] + l * 8192 + w * 1024,
                   A + (size_t)(m0 + r) * K + t * 64 + (sslot ^ srow) * 8);
    }
  };
  auto stageB = [&](int b, int t) {
#pragma unroll
    for (int l = 0; l < NJ; ++l) {
      const int r = l * 64 + w * 8 + srow;
      async_copy16((char*)&Bs[b][0] + l * 8192 + w * 1024,
                   Bw + (size_t)(n0 + r) * K + t * 64 + (sslot ^ srow) * 8);
    }
  };

  f32x4 acc[8][NJ] = {};
  GFrags<NJ> f;

#define PHASE(BS, MP, RDB, VM, ...)                                            \
  do {                                                                         \
    g_reads<NJ, MP, RDB>(&As[BS][0], &Bs[BS][0], lm, lg, wm, wn, f);           \
    __VA_ARGS__;                                                               \
    __builtin_amdgcn_s_barrier();                                              \
    __builtin_amdgcn_s_setprio(1);                                             \
    g_mfma<NJ, MP>(f, acc);                                                    \
    __builtin_amdgcn_s_setprio(0);                                             \
    waitvm<(VM)>();                                                            \
    __builtin_amdgcn_s_barrier();                                              \
  } while (0)

  const int nt = K >> 6;
  stageB(0, 0);
  stageA(0, 0);
  stageB(1, 1);
  waitvm<NJ>();
  __builtin_amdgcn_s_barrier();

#pragma unroll 1
  for (int t = 0; t < nt - 2; t += 2) {
    PHASE(0, 0, 1, 9, stageA(1, t + 1));
    PHASE(0, 1, 0, 9, stageB(0, t + 2));
    PHASE(0, 2, 0, 9, );
    PHASE(0, 3, 0, NJ, );   // drains A/B(t+1); B(t+2) stays in flight
    PHASE(1, 0, 1, 9, stageA(0, t + 2));
    PHASE(1, 1, 0, 9, stageB(1, t + 3));
    PHASE(1, 2, 0, 9, );
    PHASE(1, 3, 0, NJ, );   // drains A/B(t+2); B(t+3) stays in flight
  }
  PHASE(0, 0, 1, 9, stageA(1, nt - 1));
  PHASE(0, 1, 0, 9, );
  PHASE(0, 2, 0, 9, );
  PHASE(0, 3, 0, 0, );
  PHASE(1, 0, 1, 9, );
  PHASE(1, 1, 0, 9, );
  PHASE(1, 2, 0, 9, );
  PHASE(1, 3, 0, 9, );
#undef PHASE

#pragma unroll
  for (int mi = 0; mi < 8; ++mi) {
#pragma unroll
    for (int nj = 0; nj < NJ; ++nj) {
      const int col = n0 + wn * (NJ * 16) + nj * 16 + lm;
      const float bv = bias[col];
      const int r0 = m0 + wm * 128 + mi * 16 + lg * 4;
#pragma unroll
      for (int r = 0; r < 4; ++r) {
        const float v = acc[mi][nj][r] + bv;
        if (OUT_F32)
          reinterpret_cast<float*>(Cout)[(size_t)(r0 + r) * N + col] = v;
        else
          reinterpret_cast<bf16*>(Cout)[(size_t)(r0 + r) * N + col] = (bf16)v;
      }
    }
  }
}

// ---------------- causal flash attention ----------------
// Vt: padded [128 rows][136 B] (row d = 64 kv packed pairwise as 32 dwords + 8B pad).
// Writes: 8x ds_write_b64, affine base + e*136 (no spill); ~2x-min banks.
// Reads: 2x ds_read_b64 per fragment; bank-exact min (conflict-free).
// Ps: per-wave [16][72]; write->read ordered by __threadfence_block() (per-wave
// region; only DS ordering needed, not a cross-wave barrier).
__device__ __forceinline__ void attn_tile(
    const char* ksb, const char* vtb, bf16* psw,
    const bf16x8* qf, f32x4* acc, float* mrow, float* lrow,
    int qr0, int kv0, bool diag, int lm, int lg) {
  float p[4][4];
#pragma unroll
  for (int kt = 0; kt < 4; ++kt) {
    f32x4 s = {};
    const int r = kt * 16 + lm;
#pragma unroll
    for (int kk = 0; kk < 4; ++kk) {
      bf16x8 kf = *reinterpret_cast<const bf16x8*>(
          ksb + r * 256 + ((kk * 64 + lg * 16) ^ ((lm & 7) << 4)));
      s = __builtin_amdgcn_mfma_f32_16x16x32_bf16(qf[kk], kf, s, 0, 0, 0);
    }
    if (diag) {
      const int col = kv0 + kt * 16 + lm;
#pragma unroll
      for (int rr = 0; rr < 4; ++rr)
        p[kt][rr] = (col <= qr0 + lg * 4 + rr) ? s[rr] * SCALE_QK : -3.0e38f;
    } else {
#pragma unroll
      for (int rr = 0; rr < 4; ++rr) p[kt][rr] = s[rr] * SCALE_QK;
    }
  }
#pragma unroll
  for (int rr = 0; rr < 4; ++rr) {
    float pm = fmaxf(fmaxf(p[0][rr], p[1][rr]), fmaxf(p[2][rr], p[3][rr]));
#pragma unroll
    for (int off = 1; off < 16; off <<= 1) pm = fmaxf(pm, __shfl_xor(pm, off));
    const float mnew = fmaxf(mrow[rr], pm);
    const float sc = __expf(mrow[rr] - mnew);
    mrow[rr] = mnew;
    float sum = 0.f;
#pragma unroll
    for (int kt = 0; kt < 4; ++kt) { p[kt][rr] = __expf(p[kt][rr] - mnew); sum += p[kt][rr]; }
#pragma unroll
    for (int off = 1; off < 16; off <<= 1) sum += __shfl_xor(sum, off);
    lrow[rr] = lrow[rr] * sc + sum;
#pragma unroll
    for (int dt = 0; dt < 8; ++dt) acc[dt][rr] *= sc;
  }
#pragma unroll
  for (int kt = 0; kt < 4; ++kt)
#pragma unroll
    for (int rr = 0; rr < 4; ++rr)
      psw[(lg * 4 + rr) * 72 + kt * 16 + lm] = (bf16)p[kt][rr];
  __threadfence_block();  // order per-wave Ps writes before reads (no barrier)
#pragma unroll
  for (int kb = 0; kb < 2; ++kb) {
    bf16x8 pa = *reinterpret_cast<const bf16x8*>(&psw[lm * 72 + kb * 32 + lg * 8]);
#pragma unroll
    for (int dt = 0; dt < 8; ++dt) {
      const int d = dt * 16 + lm;
      const char* vp = vtb + d * 136 + kb * 64 + lg * 16;
      bf16x4 vlo = *reinterpret_cast<const bf16x4*>(vp);
      bf16x4 vhi = *reinterpret_cast<const bf16x4*>(vp + 8);
      bf16x8 vf = __builtin_shufflevector(vlo, vhi, 0, 1, 2, 3, 4, 5, 6, 7);
      acc[dt] = __builtin_amdgcn_mfma_f32_16x16x32_bf16(pa, vf, acc[dt], 0, 0, 0);
    }
  }
}

__global__ __launch_bounds__(256, 2) void attn_kernel(const bf16* __restrict__ qkv,
                                                      bf16* __restrict__ ctx) {
  __shared__ __align__(16) bf16 Ks[2][64 * 128];
  __shared__ __align__(16) bf16 Vt[2][128 * 68];   // 136 B/row padded
  __shared__ __align__(16) bf16 Ps[4 * 16 * 72];

  const int tid = threadIdx.x;
  const int lane = tid & 63;
  const int w = tid >> 6;
  const int lm = lane & 15;
  const int lg = lane >> 4;
  // XCD clustering: all 16 pair-blocks of one (b,h) land on one XCD so the
  // shared 1 MB K/V stream is fetched into that XCD's L2 once.
  const int bid = blockIdx.x;
  const int xcd = bid & 7;
  const int rr_ = bid >> 3;
  const int bh = xcd * 4 + (rr_ & 3);
  const int pr = rr_ >> 2;
  const int b = bh >> 4;
  const int h = bh & 15;
  const int qtA = 31 - pr;
  const int qtB = pr;

  const size_t rs = H3;
  const bf16* qbase = qkv + (size_t)b * Ss * rs + (size_t)h * HNd;
  const bf16* kbase = qbase + Hh;
  const bf16* vbase = qbase + 2 * Hh;

  const int qrA = qtA * 64 + w * 16;
  const int qrB = qtB * 64 + w * 16;

  bf16x8 qfA[4], qfB[4];
#pragma unroll
  for (int kk = 0; kk < 4; ++kk) {
    qfA[kk] = *reinterpret_cast<const bf16x8*>(qbase + (size_t)(qrA + lm) * rs + kk * 32 + lg * 8);
    qfB[kk] = *reinterpret_cast<const bf16x8*>(qbase + (size_t)(qrB + lm) * rs + kk * 32 + lg * 8);
  }

  f32x4 accA[8] = {}, accB[8] = {};
  float mA[4], lA[4], mB[4], lB[4];
#pragma unroll
  for (int r = 0; r < 4; ++r) { mA[r] = mB[r] = -3.0e38f; lA[r] = lB[r] = 0.f; }

  bf16* psw = Ps + w * 16 * 72;

  // K stage: linear LDS dest, pre-swizzled global source slot
  auto stageK = [&](char* ksb, int kv0) {
#pragma unroll
    for (int c = 0; c < 4; ++c) {
      const int ci = c * 4 + w;
      const int row = ci * 4 + lg;
      async_copy16(ksb + ci * 1024,
                   kbase + (size_t)(kv0 + row) * rs + (lm ^ (row & 7)) * 8);
    }
  };
  // V: thread (kvq = tid>>4, d8 = tid&15) loads 4 kv-rows x 8 d (issue-early)
  auto loadV = [&](int kv0, bf16x8* vr) {
    const int kvq = tid >> 4;
    const int d8 = tid & 15;
#pragma unroll
    for (int j = 0; j < 4; ++j)
      vr[j] = *reinterpret_cast<const bf16x8*>(
          vbase + (size_t)(kv0 + kvq * 4 + j) * rs + d8 * 8);
  };
  // V: pack kv-quads, 8x ds_write_b64 at base + e*136 (write-late)
  auto writeV = [&](char* vtb, const bf16x8* vr) {
    const int kvq = tid >> 4;
    const int d8 = tid & 15;
    const u16x8 a = (u16x8)vr[0], bq = (u16x8)vr[1];
    const u16x8 c = (u16x8)vr[2], dq = (u16x8)vr[3];
#pragma unroll
    for (int e = 0; e < 8; ++e) {
      uint2 pk;
      pk.x = (unsigned)a[e] | ((unsigned)bq[e] << 16);
      pk.y = (unsigned)c[e] | ((unsigned)dq[e] << 16);
      *reinterpret_cast<uint2*>(vtb + (d8 * 8 + e) * 136 + kvq * 8) = pk;
    }
  };

  bf16x8 vr[4];
  stageK((char*)Ks[0], 0);
  loadV(0, vr);
  writeV((char*)Vt[0], vr);
  __syncthreads();

  const int nkv = qtA + 1;
  for (int t = 0; t < nkv; ++t) {
    const int cur = t & 1;
    const bool pf = (t + 1 < nkv);
    if (pf) {                       // issue-early: K(t+1) glds + V(t+1) reg loads
      stageK((char*)Ks[cur ^ 1], (t + 1) * 64);
      loadV((t + 1) * 64, vr);
    }
    const int kv0 = t * 64;
    attn_tile((char*)Ks[cur], (char*)Vt[cur], psw, qfA, accA, mA, lA, qrA, kv0,
              t == qtA, lm, lg);
    if (t <= qtB)
      attn_tile((char*)Ks[cur], (char*)Vt[cur], psw, qfB, accB, mB, lB, qrB, kv0,
                t == qtB, lm, lg);
    if (pf) writeV((char*)Vt[cur ^ 1], vr);  // write-late into the other buffer
    __syncthreads();
  }

  bf16* cbase = ctx + (size_t)b * Ss * Hh + (size_t)h * HNd;
#pragma unroll
  for (int dt = 0; dt < 8; ++dt)
#pragma unroll
    for (int r = 0; r < 4; ++r) {
      cbase[(size_t)(qrA + lg * 4 + r) * Hh + dt * 16 + lm] = (bf16)(accA[dt][r] / lA[r]);
      cbase[(size_t)(qrB + lg * 4 + r) * Hh + dt * 16 + lm] = (bf16)(accB[dt][r] / lB[r]);
    }
}

extern "C" void kernel_launch(void* const* d_in, const int* in_sizes, int n_in,
                              void* d_out, int out_size, void* d_ws, size_t ws_size,
                              hipStream_t stream) {
  const float* hidden = (const float*)d_in[0];
  const float* Wqkv = (const float*)d_in[2];
  const float* bqkv = (const float*)d_in[3];
  const float* Wout = (const float*)d_in[4];
  const float* bout = (const float*)d_in[5];
  float* out = (float*)d_out;

  char* ws = (char*)d_ws;
  bf16* hid_bf = (bf16*)ws;  ws += (size_t)Mm * Hh * 2;
  bf16* wqkv_bf = (bf16*)ws; ws += (size_t)H3 * Hh * 2;
  bf16* wout_bf = (bf16*)ws; ws += (size_t)Hh * Hh * 2;
  bf16* qkv_bf = (bf16*)ws;  ws += (size_t)Mm * H3 * 2;
  bf16* ctx_bf = (bf16*)ws;  ws += (size_t)Mm * Hh * 2;

  const int n0 = Mm * Hh, n1 = H3 * Hh, n2 = Hh * Hh;
  cvt3_kernel<<<((n0 + n1 + n2) / 4 + 255) / 256, 256, 0, stream>>>(
      hidden, hid_bf, n0, Wqkv, wqkv_bf, n1, Wout, wout_bf, n2);

  // GEMM1: 256x192 tile -> grid 32x16 = 512 blocks = 2 exact rounds
  gemmW_kernel<3, 0><<<dim3(H3 / 192, Mm / 256), 512, 0, stream>>>(
      hid_bf, wqkv_bf, bqkv, qkv_bf, Mm, H3, Hh);
  attn_kernel<<<dim3(512), 256, 0, stream>>>(qkv_bf, ctx_bf);
  // GEMM2: 256x128 tile -> grid 16x16 = 256 blocks = 1 exact round
  gemmW_kernel<2, 1><<<dim3(Hh / 128, Mm / 256), 512, 0, stream>>>(
      ctx_bf, wout_bf, bout, out, Mm, Hh, Hh);
}

// Round 11
// 261.242 us; speedup vs baseline: 1.0476x; 1.0476x over previous
//
#include <hip/hip_runtime.h>

typedef __bf16 bf16;
typedef bf16 bf16x4 __attribute__((ext_vector_type(4)));
typedef bf16 bf16x8 __attribute__((ext_vector_type(8)));
typedef unsigned short u16x8 __attribute__((ext_vector_type(8)));
typedef float f32x4 __attribute__((ext_vector_type(4)));

#define Bb 2
#define Ss 2048
#define Hh 2048
#define NHh 16
#define HNd 128
#define H3 6144
#define Mm 4096
// 1/sqrt(128) * log2(e): QK^T scores scaled directly into log2 domain
#define SCALE_LOG2 0.12752039136902522f
#define DTHR 8.0f   // defer-max threshold (log2 units): P bounded by 2^8

__device__ __forceinline__ void async_copy16(void* lds, const void* g) {
  __builtin_amdgcn_global_load_lds(
      (const __attribute__((address_space(1))) unsigned int*)g,
      (__attribute__((address_space(3))) unsigned int*)lds, 16, 0, 0);
}

template <int N>
__device__ __forceinline__ void waitvm() {
  if constexpr (N == 0) asm volatile("s_waitcnt vmcnt(0)" ::: "memory");
  else if constexpr (N == 2) asm volatile("s_waitcnt vmcnt(2)" ::: "memory");
  else if constexpr (N == 3) asm volatile("s_waitcnt vmcnt(3)" ::: "memory");
  // N==9: no wait
}

// ---------------- fused fp32 -> bf16 convert (3 segments, 1 launch) ----------------
__device__ __forceinline__ void cvt4(const float* in, bf16* out, int i) {
  float4 v = *reinterpret_cast<const float4*>(in + i);
  bf16x4 o;
  o[0] = (bf16)v.x; o[1] = (bf16)v.y; o[2] = (bf16)v.z; o[3] = (bf16)v.w;
  *reinterpret_cast<bf16x4*>(out + i) = o;
}

__global__ __launch_bounds__(256) void cvt3_kernel(
    const float* __restrict__ s0, bf16* __restrict__ d0, int n0,
    const float* __restrict__ s1, bf16* __restrict__ d1, int n1,
    const float* __restrict__ s2, bf16* __restrict__ d2, int n2) {
  int i = (blockIdx.x * 256 + threadIdx.x) * 4;
  if (i < n0) cvt4(s0, d0, i);
  else if ((i -= n0) < n1) cvt4(s1, d1, i);
  else if ((i -= n1) < n2) cvt4(s2, d2, i);
}

// ---------------- 256xBN 8-phase bf16 GEMM (T1+T2+T3+T4+T5), BN = NJ*64 ----------------
template <int NJ>
struct GFrags {
  bf16x8 af[2][2];
  bf16x8 bfr[NJ][2];
};

template <int NJ, int MP, int RDB>
__device__ __forceinline__ void g_reads(const bf16* asb, const bf16* bsb,
                                        int lm, int lg, int wm, int wn,
                                        GFrags<NJ>& f) {
  if (RDB) {
#pragma unroll
    for (int nj = 0; nj < NJ; ++nj)
#pragma unroll
      for (int kk = 0; kk < 2; ++kk) {
        const int row = wn * (NJ * 16) + nj * 16 + lm;
        f.bfr[nj][kk] = *reinterpret_cast<const bf16x8*>(
            (const char*)bsb + row * 128 + ((kk * 64 + lg * 16) ^ ((lm & 7) << 4)));
      }
  }
#pragma unroll
  for (int i = 0; i < 2; ++i)
#pragma unroll
    for (int kk = 0; kk < 2; ++kk) {
      const int row = wm * 128 + (MP * 2 + i) * 16 + lm;
      f.af[i][kk] = *reinterpret_cast<const bf16x8*>(
          (const char*)asb + row * 128 + ((kk * 64 + lg * 16) ^ ((lm & 7) << 4)));
    }
}

template <int NJ, int MP>
__device__ __forceinline__ void g_mfma(const GFrags<NJ>& f, f32x4 (&acc)[8][NJ]) {
#pragma unroll
  for (int kk = 0; kk < 2; ++kk)
#pragma unroll
    for (int i = 0; i < 2; ++i)
#pragma unroll
      for (int nj = 0; nj < NJ; ++nj)
        acc[MP * 2 + i][nj] = __builtin_amdgcn_mfma_f32_16x16x32_bf16(
            f.af[i][kk], f.bfr[nj][kk], acc[MP * 2 + i][nj], 0, 0, 0);
}

template <int NJ, int OUT_F32>
__global__ __launch_bounds__(512, 2) void gemmW_kernel(
    const bf16* __restrict__ A, const bf16* __restrict__ Bw,
    const float* __restrict__ bias, void* __restrict__ Cout,
    int M, int N, int K) {
  __shared__ __align__(16) bf16 As[2][256 * 64];
  __shared__ __align__(16) bf16 Bs[2][NJ * 64 * 64];

  const int tid = threadIdx.x;
  const int lane = tid & 63;
  const int w = tid >> 6;
  const int wm = w >> 2, wn = w & 3;
  const int lm = lane & 15, lg = lane >> 4;
  const int srow = lane >> 3;
  const int sslot = lane & 7;

  // XCD column-chunk remap (bijective when gridDim.x % 8 == 0)
  const int id = blockIdx.y * gridDim.x + blockIdx.x;
  const int cpx = gridDim.x >> 3;
  const int xcd = id & 7, rem = id >> 3;
  const int bx = xcd * cpx + rem % cpx;
  const int by = rem / cpx;
  const int m0 = by * 256, n0 = bx * (NJ * 64);

  auto stageA = [&](int b, int t) {
#pragma unroll
    for (int l = 0; l < 4; ++l) {
      const int r = l * 64 + w * 8 + srow;
      async_copy16((char*)&As[b][0] + l * 8192 + w * 1024,
                   A + (size_t)(m0 + r) * K + t * 64 + (sslot ^ srow) * 8);
    }
  };
  auto stageB = [&](int b, int t) {
#pragma unroll
    for (int l = 0; l < NJ; ++l) {
      const int r = l * 64 + w * 8 + srow;
      async_copy16((char*)&Bs[b][0] + l * 8192 + w * 1024,
                   Bw + (size_t)(n0 + r) * K + t * 64 + (sslot ^ srow) * 8);
    }
  };

  f32x4 acc[8][NJ] = {};
  GFrags<NJ> f;

#define PHASE(BS, MP, RDB, VM, ...)                                            \
  do {                                                                         \
    g_reads<NJ, MP, RDB>(&As[BS][0], &Bs[BS][0], lm, lg, wm, wn, f);           \
    __VA_ARGS__;                                                               \
    __builtin_amdgcn_s_barrier();                                              \
    __builtin_amdgcn_s_setprio(1);                                             \
    g_mfma<NJ, MP>(f, acc);                                                    \
    __builtin_amdgcn_s_setprio(0);                                             \
    waitvm<(VM)>();                                                            \
    __builtin_amdgcn_s_barrier();                                              \
  } while (0)

  const int nt = K >> 6;
  stageB(0, 0);
  stageA(0, 0);
  stageB(1, 1);
  waitvm<NJ>();
  __builtin_amdgcn_s_barrier();

#pragma unroll 1
  for (int t = 0; t < nt - 2; t += 2) {
    PHASE(0, 0, 1, 9, stageA(1, t + 1));
    PHASE(0, 1, 0, 9, stageB(0, t + 2));
    PHASE(0, 2, 0, 9, );
    PHASE(0, 3, 0, NJ, );   // drains A/B(t+1); B(t+2) stays in flight
    PHASE(1, 0, 1, 9, stageA(0, t + 2));
    PHASE(1, 1, 0, 9, stageB(1, t + 3));
    PHASE(1, 2, 0, 9, );
    PHASE(1, 3, 0, NJ, );   // drains A/B(t+2); B(t+3) stays in flight
  }
  PHASE(0, 0, 1, 9, stageA(1, nt - 1));
  PHASE(0, 1, 0, 9, );
  PHASE(0, 2, 0, 9, );
  PHASE(0, 3, 0, 0, );
  PHASE(1, 0, 1, 9, );
  PHASE(1, 1, 0, 9, );
  PHASE(1, 2, 0, 9, );
  PHASE(1, 3, 0, 9, );
#undef PHASE

#pragma unroll
  for (int mi = 0; mi < 8; ++mi) {
#pragma unroll
    for (int nj = 0; nj < NJ; ++nj) {
      const int col = n0 + wn * (NJ * 16) + nj * 16 + lm;
      const float bv = bias[col];
      const int r0 = m0 + wm * 128 + mi * 16 + lg * 4;
#pragma unroll
      for (int r = 0; r < 4; ++r) {
        const float v = acc[mi][nj][r] + bv;
        if (OUT_F32)
          reinterpret_cast<float*>(Cout)[(size_t)(r0 + r) * N + col] = v;
        else
          reinterpret_cast<bf16*>(Cout)[(size_t)(r0 + r) * N + col] = (bf16)v;
      }
    }
  }
}

// ---------------- causal flash attention (R7 LDS layout + low-VALU softmax) ----------------
// Softmax in log2 domain (scores pre-scaled by 1/sqrt(d)*log2 e):
//  - row max via 3 fmax + 4-step shfl reduce
//  - defer-max (T13): skip acc rescale when no row grew > DTHR (wave-uniform __any)
//  - row sum via MFMA with all-ones B (every lane gets its row sum; no shuffles)
__device__ __forceinline__ void attn_tile(
    const char* ksb, const char* vtb, bf16* psw,
    const bf16x8* qf, f32x4* acc, f32x4& accl, float* mrow,
    int qr0, int kv0, bool diag, int lm, int lg) {
  float p[4][4];
#pragma unroll
  for (int kt = 0; kt < 4; ++kt) {
    f32x4 s = {};
    const int r = kt * 16 + lm;
#pragma unroll
    for (int kk = 0; kk < 4; ++kk) {
      bf16x8 kf = *reinterpret_cast<const bf16x8*>(
          ksb + r * 256 + ((kk * 64 + lg * 16) ^ ((lm & 7) << 4)));
      s = __builtin_amdgcn_mfma_f32_16x16x32_bf16(qf[kk], kf, s, 0, 0, 0);
    }
    if (diag) {
      const int col = kv0 + kt * 16 + lm;
#pragma unroll
      for (int rr = 0; rr < 4; ++rr)
        p[kt][rr] = (col <= qr0 + lg * 4 + rr) ? s[rr] * SCALE_LOG2 : -3.0e38f;
    } else {
#pragma unroll
      for (int rr = 0; rr < 4; ++rr) p[kt][rr] = s[rr] * SCALE_LOG2;
    }
  }
  // row max (per 16-lane group)
  float pm4[4];
#pragma unroll
  for (int rr = 0; rr < 4; ++rr) {
    float pm = fmaxf(fmaxf(p[0][rr], p[1][rr]), fmaxf(p[2][rr], p[3][rr]));
#pragma unroll
    for (int off = 1; off < 16; off <<= 1) pm = fmaxf(pm, __shfl_xor(pm, off));
    pm4[rr] = pm;
  }
  // defer-max: rescale only when some row grew beyond DTHR (uniform branch)
  const bool need = (pm4[0] > mrow[0] + DTHR) || (pm4[1] > mrow[1] + DTHR) ||
                    (pm4[2] > mrow[2] + DTHR) || (pm4[3] > mrow[3] + DTHR);
  if (__any(need)) {
#pragma unroll
    for (int rr = 0; rr < 4; ++rr) {
      const float mnew = fmaxf(mrow[rr], pm4[rr]);
      const float sc = exp2f(mrow[rr] - mnew);
      mrow[rr] = mnew;
      accl[rr] *= sc;
#pragma unroll
      for (int dt = 0; dt < 8; ++dt) acc[dt][rr] *= sc;
    }
  }
#pragma unroll
  for (int kt = 0; kt < 4; ++kt)
#pragma unroll
    for (int rr = 0; rr < 4; ++rr)
      p[kt][rr] = exp2f(p[kt][rr] - mrow[rr]);   // bounded by 2^DTHR
  // P -> per-wave LDS ([16][72] pad layout)
#pragma unroll
  for (int kt = 0; kt < 4; ++kt)
#pragma unroll
    for (int rr = 0; rr < 4; ++rr)
      psw[(lg * 4 + rr) * 72 + kt * 16 + lm] = (bf16)p[kt][rr];
  __syncthreads();
  // PV + ones-sum
  const bf16 one = (bf16)1.0f;
  const bf16x8 ones = {one, one, one, one, one, one, one, one};
#pragma unroll
  for (int kb = 0; kb < 2; ++kb) {
    bf16x8 pa = *reinterpret_cast<const bf16x8*>(&psw[lm * 72 + kb * 32 + lg * 8]);
    accl = __builtin_amdgcn_mfma_f32_16x16x32_bf16(pa, ones, accl, 0, 0, 0);
#pragma unroll
    for (int dt = 0; dt < 8; ++dt) {
      const int d = dt * 16 + lm;
      bf16x8 vf = *reinterpret_cast<const bf16x8*>(
          vtb + d * 128 + ((kb * 64 + lg * 16) ^ (((dt * 2 + (lm >> 3)) & 7) << 4)));
      acc[dt] = __builtin_amdgcn_mfma_f32_16x16x32_bf16(pa, vf, acc[dt], 0, 0, 0);
    }
  }
}

__global__ __launch_bounds__(256, 2) void attn_kernel(const bf16* __restrict__ qkv,
                                                      bf16* __restrict__ ctx) {
  __shared__ __align__(16) bf16 Ks[2][64 * 128];
  __shared__ __align__(16) bf16 Vt[2][128 * 64];
  __shared__ __align__(16) bf16 Ps[4 * 16 * 72];

  const int tid = threadIdx.x;
  const int lane = tid & 63;
  const int w = tid >> 6;
  const int lm = lane & 15;
  const int lg = lane >> 4;
  // XCD clustering: all 16 pair-blocks of one (b,h) land on one XCD so the
  // shared 1 MB K/V stream is fetched into that XCD's L2 once.
  const int bid = blockIdx.x;
  const int xcd = bid & 7;
  const int rr_ = bid >> 3;
  const int bh = xcd * 4 + (rr_ & 3);
  const int pr = rr_ >> 2;
  const int b = bh >> 4;
  const int h = bh & 15;
  const int qtA = 31 - pr;
  const int qtB = pr;

  const size_t rs = H3;
  const bf16* qbase = qkv + (size_t)b * Ss * rs + (size_t)h * HNd;
  const bf16* kbase = qbase + Hh;
  const bf16* vbase = qbase + 2 * Hh;

  const int qrA = qtA * 64 + w * 16;
  const int qrB = qtB * 64 + w * 16;

  bf16x8 qfA[4], qfB[4];
#pragma unroll
  for (int kk = 0; kk < 4; ++kk) {
    qfA[kk] = *reinterpret_cast<const bf16x8*>(qbase + (size_t)(qrA + lm) * rs + kk * 32 + lg * 8);
    qfB[kk] = *reinterpret_cast<const bf16x8*>(qbase + (size_t)(qrB + lm) * rs + kk * 32 + lg * 8);
  }

  f32x4 accA[8] = {}, accB[8] = {};
  f32x4 aclA = {}, aclB = {};
  float mA[4], mB[4];
#pragma unroll
  for (int r = 0; r < 4; ++r) { mA[r] = mB[r] = -3.0e38f; }

  bf16* psw = Ps + w * 16 * 72;

  // K stage: linear LDS dest, pre-swizzled global source slot
  auto stageK = [&](char* ksb, int kv0) {
#pragma unroll
    for (int c = 0; c < 4; ++c) {
      const int ci = c * 4 + w;
      const int row = ci * 4 + lg;
      async_copy16(ksb + ci * 1024,
                   kbase + (size_t)(kv0 + row) * rs + (lm ^ (row & 7)) * 8);
    }
  };
  // V: load 2 kv-rows x 8 d per slot into regs (issue-early)
  auto loadV = [&](int kv0, bf16x8* vr) {
#pragma unroll
    for (int jj = 0; jj < 2; ++jj) {
      const int idx = jj * 256 + tid;
      const int pair = idx >> 4;
      const int d8 = idx & 15;
      vr[jj * 2 + 0] = *reinterpret_cast<const bf16x8*>(
          vbase + (size_t)(kv0 + pair * 2) * rs + d8 * 8);
      vr[jj * 2 + 1] = *reinterpret_cast<const bf16x8*>(
          vbase + (size_t)(kv0 + pair * 2 + 1) * rs + d8 * 8);
    }
  };
  // V: pack kv-pairs to dwords, write transposed+swizzled (write-late; R7 layout)
  auto writeV = [&](char* vtb, const bf16x8* vr) {
#pragma unroll
    for (int jj = 0; jj < 2; ++jj) {
      const int idx = jj * 256 + tid;
      const int pair = idx >> 4;
      const int d8 = idx & 15;
      const u16x8 lo = (u16x8)vr[jj * 2 + 0];
      const u16x8 hi = (u16x8)vr[jj * 2 + 1];
#pragma unroll
      for (int e = 0; e < 8; ++e) {
        const unsigned pk = (unsigned)lo[e] | ((unsigned)hi[e] << 16);
        *reinterpret_cast<unsigned*>(
            vtb + (d8 * 8 + e) * 128 + ((pair * 4) ^ ((d8 & 7) << 4))) = pk;
      }
    }
  };

  bf16x8 vr[4];
  stageK((char*)Ks[0], 0);
  loadV(0, vr);
  writeV((char*)Vt[0], vr);
  __syncthreads();

  const int nkv = qtA + 1;
  for (int t = 0; t < nkv; ++t) {
    const int cur = t & 1;
    const bool pf = (t + 1 < nkv);
    if (pf) {                       // issue-early: K(t+1) glds + V(t+1) reg loads
      stageK((char*)Ks[cur ^ 1], (t + 1) * 64);
      loadV((t + 1) * 64, vr);
    }
    const int kv0 = t * 64;
    attn_tile((char*)Ks[cur], (char*)Vt[cur], psw, qfA, accA, aclA, mA, qrA, kv0,
              t == qtA, lm, lg);
    if (t <= qtB)
      attn_tile((char*)Ks[cur], (char*)Vt[cur], psw, qfB, accB, aclB, mB, qrB, kv0,
                t == qtB, lm, lg);
    if (pf) writeV((char*)Vt[cur ^ 1], vr);  // write-late into the other buffer
    __syncthreads();
  }

  bf16* cbase = ctx + (size_t)b * Ss * Hh + (size_t)h * HNd;
#pragma unroll
  for (int dt = 0; dt < 8; ++dt)
#pragma unroll
    for (int r = 0; r < 4; ++r) {
      cbase[(size_t)(qrA + lg * 4 + r) * Hh + dt * 16 + lm] = (bf16)(accA[dt][r] / aclA[r]);
      cbase[(size_t)(qrB + lg * 4 + r) * Hh + dt * 16 + lm] = (bf16)(accB[dt][r] / aclB[r]);
    }
}

extern "C" void kernel_launch(void* const* d_in, const int* in_sizes, int n_in,
                              void* d_out, int out_size, void* d_ws, size_t ws_size,
                              hipStream_t stream) {
  const float* hidden = (const float*)d_in[0];
  const float* Wqkv = (const float*)d_in[2];
  const float* bqkv = (const float*)d_in[3];
  const float* Wout = (const float*)d_in[4];
  const float* bout = (const float*)d_in[5];
  float* out = (float*)d_out;

  char* ws = (char*)d_ws;
  bf16* hid_bf = (bf16*)ws;  ws += (size_t)Mm * Hh * 2;
  bf16* wqkv_bf = (bf16*)ws; ws += (size_t)H3 * Hh * 2;
  bf16* wout_bf = (bf16*)ws; ws += (size_t)Hh * Hh * 2;
  bf16* qkv_bf = (bf16*)ws;  ws += (size_t)Mm * H3 * 2;
  bf16* ctx_bf = (bf16*)ws;  ws += (size_t)Mm * Hh * 2;

  const int n0 = Mm * Hh, n1 = H3 * Hh, n2 = Hh * Hh;
  cvt3_kernel<<<((n0 + n1 + n2) / 4 + 255) / 256, 256, 0, stream>>>(
      hidden, hid_bf, n0, Wqkv, wqkv_bf, n1, Wout, wout_bf, n2);

  // GEMM1: 256x192 tile -> grid 32x16 = 512 blocks = 2 exact rounds
  gemmW_kernel<3, 0><<<dim3(H3 / 192, Mm / 256), 512, 0, stream>>>(
      hid_bf, wqkv_bf, bqkv, qkv_bf, Mm, H3, Hh);
  attn_kernel<<<dim3(512), 256, 0, stream>>>(qkv_bf, ctx_bf);
  // GEMM2: 256x128 tile -> grid 16x16 = 256 blocks = 1 exact round
  gemmW_kernel<2, 1><<<dim3(Hh / 128, Mm / 256), 512, 0, stream>>>(
      ctx_bf, wout_bf, bout, out, Mm, Hh, Hh);
}

// Round 13
// 260.281 us; speedup vs baseline: 1.0515x; 1.0037x over previous
//
#include <hip/hip_runtime.h>

typedef __bf16 bf16;
typedef bf16 bf16x4 __attribute__((ext_vector_type(4)));
typedef bf16 bf16x8 __attribute__((ext_vector_type(8)));
typedef unsigned short u16x8 __attribute__((ext_vector_type(8)));
typedef float f32x4 __attribute__((ext_vector_type(4)));

#define Bb 2
#define Ss 2048
#define Hh 2048
#define NHh 16
#define HNd 128
#define H3 6144
#define Mm 4096
// 1/sqrt(128) * log2(e): QK^T scores scaled directly into log2 domain
#define SCALE_LOG2 0.12752039136902522f
#define DTHR 8.0f   // defer-max threshold (log2 units): P bounded by 2^8

__device__ __forceinline__ void async_copy16(void* lds, const void* g) {
  __builtin_amdgcn_global_load_lds(
      (const __attribute__((address_space(1))) unsigned int*)g,
      (__attribute__((address_space(3))) unsigned int*)lds, 16, 0, 0);
}

template <int N>
__device__ __forceinline__ void waitvm() {
  if constexpr (N == 0) asm volatile("s_waitcnt vmcnt(0)" ::: "memory");
  else if constexpr (N == 2) asm volatile("s_waitcnt vmcnt(2)" ::: "memory");
  else if constexpr (N == 3) asm volatile("s_waitcnt vmcnt(3)" ::: "memory");
  // N==9: no wait
}

// ---------------- fused fp32 -> bf16 convert (3 segments, 1 launch) ----------------
__device__ __forceinline__ void cvt4(const float* in, bf16* out, int i) {
  float4 v = *reinterpret_cast<const float4*>(in + i);
  bf16x4 o;
  o[0] = (bf16)v.x; o[1] = (bf16)v.y; o[2] = (bf16)v.z; o[3] = (bf16)v.w;
  *reinterpret_cast<bf16x4*>(out + i) = o;
}

__global__ __launch_bounds__(256) void cvt3_kernel(
    const float* __restrict__ s0, bf16* __restrict__ d0, int n0,
    const float* __restrict__ s1, bf16* __restrict__ d1, int n1,
    const float* __restrict__ s2, bf16* __restrict__ d2, int n2) {
  int i = (blockIdx.x * 256 + threadIdx.x) * 4;
  if (i < n0) cvt4(s0, d0, i);
  else if ((i -= n0) < n1) cvt4(s1, d1, i);
  else if ((i -= n1) < n2) cvt4(s2, d2, i);
}

// ---------------- 256xBN 8-phase bf16 GEMM (T1+T2+T3+T4+T5), BN = NJ*64 ----------------
template <int NJ>
struct GFrags {
  bf16x8 af[2][2];
  bf16x8 bfr[NJ][2];
};

template <int NJ, int MP, int RDB>
__device__ __forceinline__ void g_reads(const bf16* asb, const bf16* bsb,
                                        int lm, int lg, int wm, int wn,
                                        GFrags<NJ>& f) {
  if (RDB) {
#pragma unroll
    for (int nj = 0; nj < NJ; ++nj)
#pragma unroll
      for (int kk = 0; kk < 2; ++kk) {
        const int row = wn * (NJ * 16) + nj * 16 + lm;
        f.bfr[nj][kk] = *reinterpret_cast<const bf16x8*>(
            (const char*)bsb + row * 128 + ((kk * 64 + lg * 16) ^ ((lm & 7) << 4)));
      }
  }
#pragma unroll
  for (int i = 0; i < 2; ++i)
#pragma unroll
    for (int kk = 0; kk < 2; ++kk) {
      const int row = wm * 128 + (MP * 2 + i) * 16 + lm;
      f.af[i][kk] = *reinterpret_cast<const bf16x8*>(
          (const char*)asb + row * 128 + ((kk * 64 + lg * 16) ^ ((lm & 7) << 4)));
    }
}

template <int NJ, int MP>
__device__ __forceinline__ void g_mfma(const GFrags<NJ>& f, f32x4 (&acc)[8][NJ]) {
#pragma unroll
  for (int kk = 0; kk < 2; ++kk)
#pragma unroll
    for (int i = 0; i < 2; ++i)
#pragma unroll
      for (int nj = 0; nj < NJ; ++nj)
        acc[MP * 2 + i][nj] = __builtin_amdgcn_mfma_f32_16x16x32_bf16(
            f.af[i][kk], f.bfr[nj][kk], acc[MP * 2 + i][nj], 0, 0, 0);
}

template <int NJ, int OUT_F32>
__global__ __launch_bounds__(512, 2) void gemmW_kernel(
    const bf16* __restrict__ A, const bf16* __restrict__ Bw,
    const float* __restrict__ bias, void* __restrict__ Cout,
    int M, int N, int K) {
  __shared__ __align__(16) bf16 As[2][256 * 64];
  __shared__ __align__(16) bf16 Bs[2][NJ * 64 * 64];

  const int tid = threadIdx.x;
  const int lane = tid & 63;
  const int w = tid >> 6;
  const int wm = w >> 2, wn = w & 3;
  const int lm = lane & 15, lg = lane >> 4;
  const int srow = lane >> 3;
  const int sslot = lane & 7;

  // XCD column-chunk remap (bijective when gridDim.x % 8 == 0)
  const int id = blockIdx.y * gridDim.x + blockIdx.x;
  const int cpx = gridDim.x >> 3;
  const int xcd = id & 7, rem = id >> 3;
  const int bx = xcd * cpx + rem % cpx;
  const int by = rem / cpx;
  const int m0 = by * 256, n0 = bx * (NJ * 64);

  auto stageA = [&](int b, int t) {
#pragma unroll
    for (int l = 0; l < 4; ++l) {
      const int r = l * 64 + w * 8 + srow;
      async_copy16((char*)&As[b][0] + l * 8192 + w * 1024,
                   A + (size_t)(m0 + r) * K + t * 64 + (sslot ^ srow) * 8);
    }
  };
  auto stageB = [&](int b, int t) {
#pragma unroll
    for (int l = 0; l < NJ; ++l) {
      const int r = l * 64 + w * 8 + srow;
      async_copy16((char*)&Bs[b][0] + l * 8192 + w * 1024,
                   Bw + (size_t)(n0 + r) * K + t * 64 + (sslot ^ srow) * 8);
    }
  };

  f32x4 acc[8][NJ] = {};
  GFrags<NJ> f;

#define PHASE(BS, MP, RDB, VM, ...)                                            \
  do {                                                                         \
    g_reads<NJ, MP, RDB>(&As[BS][0], &Bs[BS][0], lm, lg, wm, wn, f);           \
    __VA_ARGS__;                                                               \
    __builtin_amdgcn_s_barrier();                                              \
    __builtin_amdgcn_s_setprio(1);                                             \
    g_mfma<NJ, MP>(f, acc);                                                    \
    __builtin_amdgcn_s_setprio(0);                                             \
    waitvm<(VM)>();                                                            \
    __builtin_amdgcn_s_barrier();                                              \
  } while (0)

  const int nt = K >> 6;
  stageB(0, 0);
  stageA(0, 0);
  stageB(1, 1);
  waitvm<NJ>();
  __builtin_amdgcn_s_barrier();

#pragma unroll 1
  for (int t = 0; t < nt - 2; t += 2) {
    PHASE(0, 0, 1, 9, stageA(1, t + 1));
    PHASE(0, 1, 0, 9, stageB(0, t + 2));
    PHASE(0, 2, 0, 9, );
    PHASE(0, 3, 0, NJ, );   // drains A/B(t+1); B(t+2) stays in flight
    PHASE(1, 0, 1, 9, stageA(0, t + 2));
    PHASE(1, 1, 0, 9, stageB(1, t + 3));
    PHASE(1, 2, 0, 9, );
    PHASE(1, 3, 0, NJ, );   // drains A/B(t+2); B(t+3) stays in flight
  }
  PHASE(0, 0, 1, 9, stageA(1, nt - 1));
  PHASE(0, 1, 0, 9, );
  PHASE(0, 2, 0, 9, );
  PHASE(0, 3, 0, 0, );
  PHASE(1, 0, 1, 9, );
  PHASE(1, 1, 0, 9, );
  PHASE(1, 2, 0, 9, );
  PHASE(1, 3, 0, 9, );
#undef PHASE

#pragma unroll
  for (int mi = 0; mi < 8; ++mi) {
#pragma unroll
    for (int nj = 0; nj < NJ; ++nj) {
      const int col = n0 + wn * (NJ * 16) + nj * 16 + lm;
      const float bv = bias[col];
      const int r0 = m0 + wm * 128 + mi * 16 + lg * 4;
#pragma unroll
      for (int r = 0; r < 4; ++r) {
        const float v = acc[mi][nj][r] + bv;
        if (OUT_F32)
          reinterpret_cast<float*>(Cout)[(size_t)(r0 + r) * N + col] = v;
        else
          reinterpret_cast<bf16*>(Cout)[(size_t)(r0 + r) * N + col] = (bf16)v;
      }
    }
  }
}

// ---------------- causal flash attention (R11 softmax + per-wave Ps fence) ----------------
__device__ __forceinline__ void attn_tile(
    const char* ksb, const char* vtb, bf16* psw,
    const bf16x8* qf, f32x4* acc, f32x4& accl, float* mrow,
    int qr0, int kv0, bool diag, int lm, int lg) {
  float p[4][4];
#pragma unroll
  for (int kt = 0; kt < 4; ++kt) {
    f32x4 s = {};
    const int r = kt * 16 + lm;
#pragma unroll
    for (int kk = 0; kk < 4; ++kk) {
      bf16x8 kf = *reinterpret_cast<const bf16x8*>(
          ksb + r * 256 + ((kk * 64 + lg * 16) ^ ((lm & 7) << 4)));
      s = __builtin_amdgcn_mfma_f32_16x16x32_bf16(qf[kk], kf, s, 0, 0, 0);
    }
    if (diag) {
      const int col = kv0 + kt * 16 + lm;
#pragma unroll
      for (int rr = 0; rr < 4; ++rr)
        p[kt][rr] = (col <= qr0 + lg * 4 + rr) ? s[rr] * SCALE_LOG2 : -3.0e38f;
    } else {
#pragma unroll
      for (int rr = 0; rr < 4; ++rr) p[kt][rr] = s[rr] * SCALE_LOG2;
    }
  }
  float pm4[4];
#pragma unroll
  for (int rr = 0; rr < 4; ++rr) {
    float pm = fmaxf(fmaxf(p[0][rr], p[1][rr]), fmaxf(p[2][rr], p[3][rr]));
#pragma unroll
    for (int off = 1; off < 16; off <<= 1) pm = fmaxf(pm, __shfl_xor(pm, off));
    pm4[rr] = pm;
  }
  const bool need = (pm4[0] > mrow[0] + DTHR) || (pm4[1] > mrow[1] + DTHR) ||
                    (pm4[2] > mrow[2] + DTHR) || (pm4[3] > mrow[3] + DTHR);
  if (__any(need)) {
#pragma unroll
    for (int rr = 0; rr < 4; ++rr) {
      const float mnew = fmaxf(mrow[rr], pm4[rr]);
      const float sc = exp2f(mrow[rr] - mnew);
      mrow[rr] = mnew;
      accl[rr] *= sc;
#pragma unroll
      for (int dt = 0; dt < 8; ++dt) acc[dt][rr] *= sc;
    }
  }
#pragma unroll
  for (int kt = 0; kt < 4; ++kt)
#pragma unroll
    for (int rr = 0; rr < 4; ++rr)
      p[kt][rr] = exp2f(p[kt][rr] - mrow[rr]);
#pragma unroll
  for (int kt = 0; kt < 4; ++kt)
#pragma unroll
    for (int rr = 0; rr < 4; ++rr)
      psw[(lg * 4 + rr) * 72 + kt * 16 + lm] = (bf16)p[kt][rr];
  __threadfence_block();  // per-wave Ps write->read ordering (pattern proven R10)
  const bf16 one = (bf16)1.0f;
  const bf16x8 ones = {one, one, one, one, one, one, one, one};
#pragma unroll
  for (int kb = 0; kb < 2; ++kb) {
    bf16x8 pa = *reinterpret_cast<const bf16x8*>(&psw[lm * 72 + kb * 32 + lg * 8]);
    accl = __builtin_amdgcn_mfma_f32_16x16x32_bf16(pa, ones, accl, 0, 0, 0);
#pragma unroll
    for (int dt = 0; dt < 8; ++dt) {
      const int d = dt * 16 + lm;
      bf16x8 vf = *reinterpret_cast<const bf16x8*>(
          vtb + d * 128 + ((kb * 64 + lg * 16) ^ (((dt * 2 + (lm >> 3)) & 7) << 4)));
      acc[dt] = __builtin_amdgcn_mfma_f32_16x16x32_bf16(pa, vf, acc[dt], 0, 0, 0);
    }
  }
}

__global__ __launch_bounds__(256, 2) void attn_kernel(const bf16* __restrict__ qkv,
                                                      bf16* __restrict__ ctx) {
  __shared__ __align__(16) bf16 Ks[2][64 * 128];
  __shared__ __align__(16) bf16 Vt[2][128 * 64];
  __shared__ __align__(16) bf16 Ps[4 * 16 * 72];

  const int tid = threadIdx.x;
  const int lane = tid & 63;
  const int w = tid >> 6;
  const int lm = lane & 15;
  const int lg = lane >> 4;
  // XCD clustering: all 16 pair-blocks of one (b,h) land on one XCD (L2 reuse)
  const int bid = blockIdx.x;
  const int xcd = bid & 7;
  const int rr_ = bid >> 3;
  const int bh = xcd * 4 + (rr_ & 3);
  const int pr = rr_ >> 2;
  const int b = bh >> 4;
  const int h = bh & 15;
  const int qtA = 31 - pr;
  const int qtB = pr;

  const size_t rs = H3;
  const bf16* qbase = qkv + (size_t)b * Ss * rs + (size_t)h * HNd;
  const bf16* kbase = qbase + Hh;
  const bf16* vbase = qbase + 2 * Hh;

  const int qrA = qtA * 64 + w * 16;
  const int qrB = qtB * 64 + w * 16;

  bf16x8 qfA[4], qfB[4];
#pragma unroll
  for (int kk = 0; kk < 4; ++kk) {
    qfA[kk] = *reinterpret_cast<const bf16x8*>(qbase + (size_t)(qrA + lm) * rs + kk * 32 + lg * 8);
    qfB[kk] = *reinterpret_cast<const bf16x8*>(qbase + (size_t)(qrB + lm) * rs + kk * 32 + lg * 8);
  }

  f32x4 accA[8] = {}, accB[8] = {};
  f32x4 aclA = {}, aclB = {};
  float mA[4], mB[4];
#pragma unroll
  for (int r = 0; r < 4; ++r) { mA[r] = mB[r] = -3.0e38f; }

  bf16* psw = Ps + w * 16 * 72;

  auto stageK = [&](char* ksb, int kv0) {
#pragma unroll
    for (int c = 0; c < 4; ++c) {
      const int ci = c * 4 + w;
      const int row = ci * 4 + lg;
      async_copy16(ksb + ci * 1024,
                   kbase + (size_t)(kv0 + row) * rs + (lm ^ (row & 7)) * 8);
    }
  };
  auto loadV = [&](int kv0, bf16x8* vr) {
#pragma unroll
    for (int jj = 0; jj < 2; ++jj) {
      const int idx = jj * 256 + tid;
      const int pair = idx >> 4;
      const int d8 = idx & 15;
      vr[jj * 2 + 0] = *reinterpret_cast<const bf16x8*>(
          vbase + (size_t)(kv0 + pair * 2) * rs + d8 * 8);
      vr[jj * 2 + 1] = *reinterpret_cast<const bf16x8*>(
          vbase + (size_t)(kv0 + pair * 2 + 1) * rs + d8 * 8);
    }
  };
  auto writeV = [&](char* vtb, const bf16x8* vr) {
#pragma unroll
    for (int jj = 0; jj < 2; ++jj) {
      const int idx = jj * 256 + tid;
      const int pair = idx >> 4;
      const int d8 = idx & 15;
      const u16x8 lo = (u16x8)vr[jj * 2 + 0];
      const u16x8 hi = (u16x8)vr[jj * 2 + 1];
#pragma unroll
      for (int e = 0; e < 8; ++e) {
        const unsigned pk = (unsigned)lo[e] | ((unsigned)hi[e] << 16);
        *reinterpret_cast<unsigned*>(
            vtb + (d8 * 8 + e) * 128 + ((pair * 4) ^ ((d8 & 7) << 4))) = pk;
      }
    }
  };

  bf16x8 vr[4];
  stageK((char*)Ks[0], 0);
  loadV(0, vr);
  writeV((char*)Vt[0], vr);
  __syncthreads();

  const int nkv = qtA + 1;
  for (int t = 0; t < nkv; ++t) {
    const int cur = t & 1;
    const bool pf = (t + 1 < nkv);
    if (pf) {
      stageK((char*)Ks[cur ^ 1], (t + 1) * 64);
      loadV((t + 1) * 64, vr);
    }
    const int kv0 = t * 64;
    attn_tile((char*)Ks[cur], (char*)Vt[cur], psw, qfA, accA, aclA, mA, qrA, kv0,
              t == qtA, lm, lg);
    if (t <= qtB)
      attn_tile((char*)Ks[cur], (char*)Vt[cur], psw, qfB, accB, aclB, mB, qrB, kv0,
                t == qtB, lm, lg);
    if (pf) writeV((char*)Vt[cur ^ 1], vr);
    __syncthreads();
  }

  bf16* cbase = ctx + (size_t)b * Ss * Hh + (size_t)h * HNd;
#pragma unroll
  for (int dt = 0; dt < 8; ++dt)
#pragma unroll
    for (int r = 0; r < 4; ++r) {
      cbase[(size_t)(qrA + lg * 4 + r) * Hh + dt * 16 + lm] = (bf16)(accA[dt][r] / aclA[r]);
      cbase[(size_t)(qrB + lg * 4 + r) * Hh + dt * 16 + lm] = (bf16)(accB[dt][r] / aclB[r]);
    }
}

extern "C" void kernel_launch(void* const* d_in, const int* in_sizes, int n_in,
                              void* d_out, int out_size, void* d_ws, size_t ws_size,
                              hipStream_t stream) {
  const float* hidden = (const float*)d_in[0];
  const float* Wqkv = (const float*)d_in[2];
  const float* bqkv = (const float*)d_in[3];
  const float* Wout = (const float*)d_in[4];
  const float* bout = (const float*)d_in[5];
  float* out = (float*)d_out;

  char* ws = (char*)d_ws;
  bf16* hid_bf = (bf16*)ws;  ws += (size_t)Mm * Hh * 2;
  bf16* wqkv_bf = (bf16*)ws; ws += (size_t)H3 * Hh * 2;
  bf16* wout_bf = (bf16*)ws; ws += (size_t)Hh * Hh * 2;
  bf16* qkv_bf = (bf16*)ws;  ws += (size_t)Mm * H3 * 2;
  bf16* ctx_bf = (bf16*)ws;  ws += (size_t)Mm * Hh * 2;

  const int n0 = Mm * Hh, n1 = H3 * Hh, n2 = Hh * Hh;
  cvt3_kernel<<<((n0 + n1 + n2) / 4 + 255) / 256, 256, 0, stream>>>(
      hidden, hid_bf, n0, Wqkv, wqkv_bf, n1, Wout, wout_bf, n2);

  // GEMM1: 256x192 tile -> grid 32x16 = 512 blocks = 2 exact rounds
  gemmW_kernel<3, 0><<<dim3(H3 / 192, Mm / 256), 512, 0, stream>>>(
      hid_bf, wqkv_bf, bqkv, qkv_bf, Mm, H3, Hh);
  attn_kernel<<<dim3(512), 256, 0, stream>>>(qkv_bf, ctx_bf);
  // GEMM2: 256x128 tile -> grid 16x16 = 256 blocks = 1 exact round
  gemmW_kernel<2, 1><<<dim3(Hh / 128, Mm / 256), 512, 0, stream>>>(
      ctx_bf, wout_bf, bout, out, Mm, Hh, Hh);
}